// Round 7
// baseline (56.497 us; speedup 1.0000x reference)
//
#include <hip/hip_runtime.h>

#define NC 20
#define NCELL 49
#define NGT 32
#define NIMG 8192
#define CPB 256                     // cells per block, 1 cell (2 boxes) per thread
#define NBLK (NIMG * NCELL / CPB)   // 1568, exact
#define NSPAN 7                     // images spanned by 256 cells (off<=48: ceil(304/49)=7)
#define L2E 1.44269504088896f
#define LN2 0.69314718055995f
#define LAMBDA_COORD 5.0f
#define LAMBDA_NOOBJ 0.5f
#define EPS_IOU 1e-6f

// S-form argmax: S = pa+eps+ga; iou = in/(S-in), monotone in in/S, so
// in_j*bS > bin*S_j orders identically to IoU. Init (-1,1): j=0 always wins,
// strict > thereafter => first-index argmax (jnp semantics).
// Explicit ?: to force v_cndmask (never exec-mask branches).
#define UPD(g, ga_, j_) do {                                            \
    float iw0 = fmaxf(fminf(px2_0, (g).z) - fmaxf(px1_0, (g).x), 0.f);  \
    float ih0 = fmaxf(fminf(py2_0, (g).w) - fmaxf(py1_0, (g).y), 0.f);  \
    float in0 = iw0 * ih0;                                              \
    float S0  = pa0e + (ga_);                                           \
    bool  c0  = in0 * bS0 > bin0 * S0;                                  \
    bin0 = c0 ? in0 : bin0; bS0 = c0 ? S0 : bS0; bi0 = c0 ? (j_) : bi0; \
    float iw1 = fmaxf(fminf(px2_1, (g).z) - fmaxf(px1_1, (g).x), 0.f);  \
    float ih1 = fmaxf(fminf(py2_1, (g).w) - fmaxf(py1_1, (g).y), 0.f);  \
    float in1 = iw1 * ih1;                                              \
    float S1  = pa1e + (ga_);                                           \
    bool  c1  = in1 * bS1 > bin1 * S1;                                  \
    bin1 = c1 ? in1 : bin1; bS1 = c1 ? S1 : bS1; bi1 = c1 ? (j_) : bi1; \
} while (0)

__global__ __launch_bounds__(256) void yolo_main_kernel(
    const float* __restrict__ outputs,     // [N, 49, 30]
    const float* __restrict__ gt_boxes,    // [N, 32, 4]
    const int*   __restrict__ gt_labels,   // [N, 32]
    float* __restrict__ out)               // [1]
{
    __shared__ float4   s_act4[CPB * 30 / 4];   // 30720 B
    __shared__ float4   s_gtc[NSPAN * NGT];     //  3584 B: x1,y1,x2,y2
    __shared__ float    s_ga [NSPAN * NGT];     //   896 B: gt area
    __shared__ float    s_fm [NSPAN * NC];      //   560 B: multihot as floats
    __shared__ unsigned s_mask[NSPAN];
    __shared__ float    s_w[4];

    const int tid = threadIdx.x;
    const unsigned base   = blockIdx.x * CPB;
    const unsigned img_lo = base / NCELL;
    const unsigned off    = base - img_lo * NCELL;    // 0..48

    if (tid < NSPAN * NC) s_fm[tid] = 0.f;
    if (tid < NSPAN) s_mask[tid] = 0u;
    __syncthreads();

    // ---- stage: acts (all threads), GT corners (tid<224), labels (tid>=224) ----
    {
        const float4* asrc = reinterpret_cast<const float4*>(outputs)
                           + (size_t)blockIdx.x * (CPB * 30 / 4);
        #pragma unroll
        for (int k = 0; k < 8; ++k) {
            int i = tid + k * 256;
            if (i < CPB * 30 / 4) s_act4[i] = asrc[i];
        }
    }
    if (tid < NSPAN * NGT) {
        const unsigned g = tid >> 5, img = img_lo + g;
        if (img < NIMG) {
            float4 b = reinterpret_cast<const float4*>(gt_boxes)[img * NGT + (tid & 31)];
            s_gtc[tid] = make_float4(fmaf(b.z, -0.5f, b.x), fmaf(b.w, -0.5f, b.y),
                                     fmaf(b.z,  0.5f, b.x), fmaf(b.w,  0.5f, b.y));
            s_ga[tid] = b.z * b.w;
        }
    } else {
        const int t2 = tid - NSPAN * NGT;     // 0..31
        #pragma unroll
        for (int g = 0; g < NSPAN; ++g) {
            const unsigned img = img_lo + g;
            if (img < NIMG) {
                int lab = gt_labels[img * NGT + t2];
                atomicOr(&s_mask[g], 1u << lab);
                s_fm[g * NC + lab] = 1.0f;    // benign races: all write 1.0f
            }
        }
    }
    __syncthreads();

    // ---- per-thread: one cell, both boxes ----
    const unsigned rel = ((off + (unsigned)tid) * 1339u) >> 16;   // /49, arg<343
    const float* af = reinterpret_cast<const float*>(s_act4) + tid * 30;

    // CE: masked-sum via float-mask FMA; exp2-domain softmax
    float2 c[10];
    const float2* a2c = reinterpret_cast<const float2*>(af + 10);
    const float2* fm2 = reinterpret_cast<const float2*>(s_fm + rel * NC);
    float mx = -3.402823466e38f, sel = 0.f;
    #pragma unroll
    for (int k = 0; k < 10; ++k) {
        float2 v = a2c[k], m = fm2[k];
        c[k] = v;
        mx  = fmaxf(mx, fmaxf(v.x, v.y));
        sel = fmaf(m.x, v.x, sel);
        sel = fmaf(m.y, v.y, sel);
    }
    const float mxl = mx * L2E;
    float ss = 0.f;
    #pragma unroll
    for (int k = 0; k < 10; ++k) {
        ss += __builtin_amdgcn_exp2f(fmaf(c[k].x, L2E, -mxl));
        ss += __builtin_amdgcn_exp2f(fmaf(c[k].y, L2E, -mxl));
    }
    const float lse = fmaf(__builtin_amdgcn_logf(ss), LN2, mx);   // mx + ln2*log2(ss)
    const float ce  = (float)__popc(s_mask[rel]) * lse - sel;

    // box registers (address-based, no selects)
    const float cx0 = af[0], cy0 = af[1], w0 = af[2], h0 = af[3], cf0 = af[4];
    const float cx1 = af[5], cy1 = af[6], w1 = af[7], h1 = af[8], cf1 = af[9];
    const float px1_0 = fmaf(w0, -0.5f, cx0), py1_0 = fmaf(h0, -0.5f, cy0);
    const float px2_0 = fmaf(w0,  0.5f, cx0), py2_0 = fmaf(h0,  0.5f, cy0);
    const float px1_1 = fmaf(w1, -0.5f, cx1), py1_1 = fmaf(h1, -0.5f, cy1);
    const float px2_1 = fmaf(w1,  0.5f, cx1), py2_1 = fmaf(h1,  0.5f, cy1);
    const float pa0e = w0 * h0 + EPS_IOU, pa1e = w1 * h1 + EPS_IOU;

    // IoU argmax: GT loads shared across both box chains
    const float4* gtc = s_gtc + rel * NGT;
    const float*  gab = s_ga  + rel * NGT;
    float bin0 = -1.f, bS0 = 1.f, bin1 = -1.f, bS1 = 1.f;
    int bi0 = 0, bi1 = 0;
    #pragma unroll 4
    for (int jc = 0; jc < NGT; jc += 4) {
        float4 g0 = gtc[jc], g1 = gtc[jc + 1], g2 = gtc[jc + 2], g3 = gtc[jc + 3];
        float4 ar = *reinterpret_cast<const float4*>(gab + jc);
        UPD(g0, ar.x, jc);
        UPD(g1, ar.y, jc + 1);
        UPD(g2, ar.z, jc + 2);
        UPD(g3, ar.w, jc + 3);
    }

    // epilogue: recover matched mid/dims from corners
    float term0, term1;
    if (bin0 > 0.f) {
        float4 g = gtc[bi0];
        const float iou = __fdividef(bin0, bS0 - bin0);
        const float dx = cx0 - (g.x + g.z) * 0.5f;
        const float dy = cy0 - (g.y + g.w) * 0.5f;
        const float dw = sqrtf(w0) - sqrtf(g.z - g.x);
        const float dh = sqrtf(h0) - sqrtf(g.w - g.y);
        term0 = LAMBDA_COORD * (dx * dx + dy * dy + dw * dw + dh * dh)
              + (cf0 - iou) * (cf0 - iou) + ce;
    } else {
        term0 = LAMBDA_NOOBJ * cf0 * cf0;
    }
    if (bin1 > 0.f) {
        float4 g = gtc[bi1];
        const float iou = __fdividef(bin1, bS1 - bin1);
        const float dx = cx1 - (g.x + g.z) * 0.5f;
        const float dy = cy1 - (g.y + g.w) * 0.5f;
        const float dw = sqrtf(w1) - sqrtf(g.z - g.x);
        const float dh = sqrtf(h1) - sqrtf(g.w - g.y);
        term1 = LAMBDA_COORD * (dx * dx + dy * dy + dw * dw + dh * dh)
              + (cf1 - iou) * (cf1 - iou) + ce;
    } else {
        term1 = LAMBDA_NOOBJ * cf1 * cf1;
    }
    float partial = term0 + term1;

    // ---- block reduce -> one atomic per block ----
    #pragma unroll
    for (int o = 32; o > 0; o >>= 1)
        partial += __shfl_down(partial, o);
    if ((tid & 63) == 0) s_w[tid >> 6] = partial;
    __syncthreads();
    if (tid == 0)
        atomicAdd(out, (s_w[0] + s_w[1] + s_w[2] + s_w[3]) * (1.0f / (float)NIMG));
}

extern "C" void kernel_launch(void* const* d_in, const int* in_sizes, int n_in,
                              void* d_out, int out_size, void* d_ws, size_t ws_size,
                              hipStream_t stream) {
    const float* outputs   = (const float*)d_in[0];
    const float* gt_boxes  = (const float*)d_in[1];
    const int*   gt_labels = (const int*)d_in[2];
    float* out = (float*)d_out;

    hipMemsetAsync(out, 0, sizeof(float), stream);
    yolo_main_kernel<<<NBLK, 256, 0, stream>>>(outputs, gt_boxes, gt_labels, out);
}